// Round 2
// baseline (794.847 us; speedup 1.0000x reference)
//
#include <hip/hip_runtime.h>
#include <hip/hip_bf16.h>
#include <stdint.h>

#define SEQ 2048
#define HIDDEN 4096
#define NHEAD 32
#define NKVH 8
#define HDIM 128
#define NQT (SEQ / 64)
#define SCALE 0.08838834764831845f

typedef __bf16 bf16x8 __attribute__((ext_vector_type(8)));
typedef float floatx4 __attribute__((ext_vector_type(4)));

__device__ inline float bf2f(unsigned int u16) {
    union { unsigned int i; float f; } x;
    x.i = u16 << 16;
    return x.f;
}
__device__ inline unsigned short f2bf(float f) {
    union { float f; unsigned int u; } x;
    x.f = f;
    unsigned int r = x.u + 0x7FFF + ((x.u >> 16) & 1);   // RNE; finite inputs
    return (unsigned short)(r >> 16);
}

// fp32 -> bf16 cast, 4 elems/thread
__global__ __launch_bounds__(256) void cast_f32_bf16(const float* __restrict__ s,
                                                     unsigned short* __restrict__ d, int n4) {
    int i = blockIdx.x * 256 + threadIdx.x;
    if (i < n4) {
        float4 v = ((const float4*)s)[i];
        ushort4 o;
        o.x = f2bf(v.x); o.y = f2bf(v.y); o.z = f2bf(v.z); o.w = f2bf(v.w);
        ((ushort4*)d)[i] = o;
    }
}

__device__ inline void storeC(float* p, float v) { *p = v; }
__device__ inline void storeC(unsigned short* p, float v) { *p = f2bf(v); }

// async 16B global->LDS; within a wave LDS dest must be base + lane*16
#define GLL16(gp, lp) __builtin_amdgcn_global_load_lds( \
    (const __attribute__((address_space(1))) unsigned int*)(gp), \
    (__attribute__((address_space(3))) unsigned int*)(lp), 16, 0, 0)

// C[m][n] = sum_k A[m][k]*B[n][k]; A: MxK bf16 row-major, B: NxK bf16 row-major.
// 128x128 tile, BK=32, 4 waves 2x2, wave does 64x64 via 4x4 of 16x16x32 MFMA.
// TRANSOUT: write C transposed as bf16 CT[n][m] (packed 4-row 8B stores).
template <typename OutT, bool TRANSOUT = false>
__global__ __launch_bounds__(256) void gemm_nt_mfma(const unsigned short* __restrict__ A,
                                                    const unsigned short* __restrict__ B,
                                                    OutT* __restrict__ C,
                                                    int M, int N, int K) {
    __shared__ unsigned short As[128 * 32];
    __shared__ unsigned short Bs[128 * 32];
    const int tid = threadIdx.x;
    const int lane = tid & 63;
    const int w = tid >> 6;
    const int m0 = blockIdx.y * 128, n0 = blockIdx.x * 128;
    const int wr = (w >> 1) * 64, wc = (w & 1) * 64;
    const int srow = tid >> 2;
    const int scol = (tid & 3) * 8;
    const int quad = lane >> 4, l16 = lane & 15;

    floatx4 acc[4][4] = {};

    for (int k0 = 0; k0 < K; k0 += 32) {
        __syncthreads();
        const unsigned short* gA = A + (size_t)(m0 + srow) * K + k0 + scol;
        const unsigned short* gB = B + (size_t)(n0 + srow) * K + k0 + scol;
        GLL16(gA,                  As + srow * 32 + scol);
        GLL16(gA + (size_t)64 * K, As + (64 + srow) * 32 + scol);
        GLL16(gB,                  Bs + srow * 32 + scol);
        GLL16(gB + (size_t)64 * K, Bs + (64 + srow) * 32 + scol);
        __syncthreads();

        bf16x8 af[4], bg[4];
        #pragma unroll
        for (int i = 0; i < 4; ++i)
            af[i] = *(const bf16x8*)(As + (wr + i * 16 + l16) * 32 + quad * 8);
        #pragma unroll
        for (int j = 0; j < 4; ++j)
            bg[j] = *(const bf16x8*)(Bs + (wc + j * 16 + l16) * 32 + quad * 8);
        #pragma unroll
        for (int i = 0; i < 4; ++i)
            #pragma unroll
            for (int j = 0; j < 4; ++j)
                acc[i][j] = __builtin_amdgcn_mfma_f32_16x16x32_bf16(af[i], bg[j], acc[i][j], 0, 0, 0);
    }

    // C/D layout: col = lane&15, row = quad*4 + reg
    #pragma unroll
    for (int i = 0; i < 4; ++i) {
        #pragma unroll
        for (int j = 0; j < 4; ++j) {
            int col = n0 + wc + j * 16 + l16;
            int rowb = m0 + wr + i * 16 + quad * 4;
            if constexpr (TRANSOUT) {
                ushort4 pk;
                pk.x = f2bf(acc[i][j][0]);
                pk.y = f2bf(acc[i][j][1]);
                pk.z = f2bf(acc[i][j][2]);
                pk.w = f2bf(acc[i][j][3]);
                *(ushort4*)&C[(size_t)col * M + rowb] = pk;
            } else {
                #pragma unroll
                for (int r = 0; r < 4; ++r)
                    storeC(&C[(size_t)(rowb + r) * N + col], acc[i][j][r]);
            }
        }
    }
}

// Fused K+V projection GEMM. A: [SEQ][HIDDEN] bf16; B: [2048][HIDDEN] bf16 where
// rows [0,1024) are wk and rows [1024,2048) are wv. Main loop identical to
// gemm_nt_mfma. Epilogue routes block-uniformly on n0:
//   n0 < 1024 -> K path: kb[row][col] bf16 (ld = 1024)
//   n0 >= 1024 -> V path: vtb[(col-1024)*SEQ + row] transposed bf16 (packed 8B)
__global__ __launch_bounds__(256) void gemm_kv_mfma(const unsigned short* __restrict__ A,
                                                    const unsigned short* __restrict__ B,
                                                    unsigned short* __restrict__ Ck,
                                                    unsigned short* __restrict__ Cvt) {
    const int M = SEQ, K = HIDDEN;
    __shared__ unsigned short As[128 * 32];
    __shared__ unsigned short Bs[128 * 32];
    const int tid = threadIdx.x;
    const int lane = tid & 63;
    const int w = tid >> 6;
    const int m0 = blockIdx.y * 128, n0 = blockIdx.x * 128;
    const int wr = (w >> 1) * 64, wc = (w & 1) * 64;
    const int srow = tid >> 2;
    const int scol = (tid & 3) * 8;
    const int quad = lane >> 4, l16 = lane & 15;

    floatx4 acc[4][4] = {};

    for (int k0 = 0; k0 < K; k0 += 32) {
        __syncthreads();
        const unsigned short* gA = A + (size_t)(m0 + srow) * K + k0 + scol;
        const unsigned short* gB = B + (size_t)(n0 + srow) * K + k0 + scol;
        GLL16(gA,                  As + srow * 32 + scol);
        GLL16(gA + (size_t)64 * K, As + (64 + srow) * 32 + scol);
        GLL16(gB,                  Bs + srow * 32 + scol);
        GLL16(gB + (size_t)64 * K, Bs + (64 + srow) * 32 + scol);
        __syncthreads();

        bf16x8 af[4], bg[4];
        #pragma unroll
        for (int i = 0; i < 4; ++i)
            af[i] = *(const bf16x8*)(As + (wr + i * 16 + l16) * 32 + quad * 8);
        #pragma unroll
        for (int j = 0; j < 4; ++j)
            bg[j] = *(const bf16x8*)(Bs + (wc + j * 16 + l16) * 32 + quad * 8);
        #pragma unroll
        for (int i = 0; i < 4; ++i)
            #pragma unroll
            for (int j = 0; j < 4; ++j)
                acc[i][j] = __builtin_amdgcn_mfma_f32_16x16x32_bf16(af[i], bg[j], acc[i][j], 0, 0, 0);
    }

    if (n0 < NKVH * HDIM) {
        const int N = NKVH * HDIM;
        #pragma unroll
        for (int i = 0; i < 4; ++i) {
            #pragma unroll
            for (int j = 0; j < 4; ++j) {
                int col = n0 + wc + j * 16 + l16;
                int rowb = m0 + wr + i * 16 + quad * 4;
                #pragma unroll
                for (int r = 0; r < 4; ++r)
                    Ck[(size_t)(rowb + r) * N + col] = f2bf(acc[i][j][r]);
            }
        }
    } else {
        #pragma unroll
        for (int i = 0; i < 4; ++i) {
            #pragma unroll
            for (int j = 0; j < 4; ++j) {
                int col = n0 - NKVH * HDIM + wc + j * 16 + l16;
                int rowb = m0 + wr + i * 16 + quad * 4;
                ushort4 pk;
                pk.x = f2bf(acc[i][j][0]);
                pk.y = f2bf(acc[i][j][1]);
                pk.z = f2bf(acc[i][j][2]);
                pk.w = f2bf(acc[i][j][3]);
                *(ushort4*)&Cvt[(size_t)col * M + rowb] = pk;
            }
        }
    }
}

// In-place RoPE on bf16 [SEQ][nh*HDIM]; cos/sin fp32, cos[s][d]==cos[s][d+64].
__global__ __launch_bounds__(256) void rope_bf16(unsigned short* __restrict__ x,
                                                 const float* __restrict__ cosb,
                                                 const float* __restrict__ sinb,
                                                 int nh) {
    int idx = blockIdx.x * 256 + threadIdx.x;
    int d = idx & 63;
    int t = idx >> 6;
    int h = t % nh;
    int s = t / nh;
    float cs = cosb[s * HDIM + d];
    float sn = sinb[s * HDIM + d];
    unsigned short* p = x + (size_t)s * nh * HDIM + h * HDIM + d;
    float x1 = bf2f(p[0]), x2 = bf2f(p[64]);
    p[0]  = f2bf(x1 * cs - x2 * sn);
    p[64] = f2bf(x2 * cs + x1 * sn);
}

// MFMA flash attention. grid (NQT, NHEAD), block 256 (4 waves).
// Block: head h, q-rows s0..s0+63; wave w owns q-rows s0+16w .. +16.
// q: bf16 [SEQ][NHEAD*HDIM] (roped); k: bf16 [SEQ][NKVH*HDIM] (roped);
// vt: bf16 [NKVH*HDIM][SEQ] (V transposed); ao: bf16 [SEQ][NHEAD*HDIM].
__global__ __launch_bounds__(256) void attn_mfma(const unsigned short* __restrict__ qg,
                                                 const unsigned short* __restrict__ kgb,
                                                 const unsigned short* __restrict__ vtg,
                                                 unsigned short* __restrict__ ao) {
    __shared__ unsigned short Ks[64 * 128];   // [key][dim], chunk-swizzled
    __shared__ unsigned short Vs[128 * 64];   // [dim][key], chunk-swizzled
    __shared__ unsigned short Ps[4][16 * 64]; // wave-private P, chunk-swizzled
    const int h = blockIdx.y;
    const int qt = (NQT - 1) - blockIdx.x;    // long (high-qt) blocks dispatch first
    const int s0 = qt * 64;
    const int kvh = h >> 2;                   // NHEAD/NKVH = 4
    const int tid = threadIdx.x;
    const int w = tid >> 6, lane = tid & 63;
    const int quad = lane >> 4, l16 = lane & 15;

    // Q fragments straight from global (invariant over k-tiles)
    bf16x8 aq[4];
    {
        const unsigned short* qrowp = qg + (size_t)(s0 + w * 16 + l16) * (NHEAD * HDIM) + h * HDIM;
        #pragma unroll
        for (int ks = 0; ks < 4; ++ks)
            aq[ks] = *(const bf16x8*)(qrowp + ks * 32 + quad * 8);
    }

    floatx4 acc_o[8] = {};
    float m_r[4], l_r[4];
    #pragma unroll
    for (int r = 0; r < 4; ++r) { m_r[r] = -1e30f; l_r[r] = 0.f; }

    const int srow16 = tid >> 4, sc16 = tid & 15;   // K staging: 16 rows x 16 chunks / call
    const int sdim8 = tid >> 3, skc8 = tid & 7;     // V staging: 32 dims x 8 chunks / call

    for (int t = 0; t <= qt; ++t) {
        __syncthreads();   // prior tile's LDS reads complete
        #pragma unroll
        for (int rl = 0; rl < 4; ++rl) {
            int key = rl * 16 + srow16;
            int cg = sc16 ^ (key & 7);   // swizzle on global side
            const unsigned short* gp = kgb + (size_t)(t * 64 + key) * (NKVH * HDIM) + kvh * HDIM + cg * 8;
            GLL16(gp, Ks + key * 128 + sc16 * 8);
        }
        #pragma unroll
        for (int rl = 0; rl < 4; ++rl) {
            int dim = rl * 32 + sdim8;
            int kg2 = skc8 ^ (dim & 7);
            const unsigned short* gp = vtg + (size_t)(kvh * HDIM + dim) * SEQ + t * 64 + kg2 * 8;
            GLL16(gp, Vs + dim * 64 + skc8 * 8);
        }
        __syncthreads();   // drains vmcnt -> tiles valid

        // S = Q K^T  (16 MFMAs)
        floatx4 acc_s[4] = {};
        #pragma unroll
        for (int ks = 0; ks < 4; ++ks)
            #pragma unroll
            for (int jt = 0; jt < 4; ++jt) {
                bf16x8 bk = *(const bf16x8*)(Ks + (jt * 16 + l16) * 128 +
                                             (((ks * 4 + quad) ^ (l16 & 7)) * 8));
                acc_s[jt] = __builtin_amdgcn_mfma_f32_16x16x32_bf16(aq[ks], bk, acc_s[jt], 0, 0, 0);
            }

        float s_v[4][4];
        #pragma unroll
        for (int jt = 0; jt < 4; ++jt)
            #pragma unroll
            for (int r = 0; r < 4; ++r)
                s_v[jt][r] = acc_s[jt][r] * SCALE;
        if (t == qt) {   // diagonal tile: causal mask (block-uniform branch)
            #pragma unroll
            for (int jt = 0; jt < 4; ++jt) {
                int key = t * 64 + jt * 16 + l16;
                #pragma unroll
                for (int r = 0; r < 4; ++r) {
                    int qrow = s0 + w * 16 + quad * 4 + r;
                    if (key > qrow) s_v[jt][r] = -1e30f;
                }
            }
        }

        // online softmax; row r lives in lanes sharing quad, spread over l16
        float p_v[4][4];
        #pragma unroll
        for (int r = 0; r < 4; ++r) {
            float v = fmaxf(fmaxf(s_v[0][r], s_v[1][r]), fmaxf(s_v[2][r], s_v[3][r]));
            #pragma unroll
            for (int off = 1; off < 16; off <<= 1) v = fmaxf(v, __shfl_xor(v, off));
            float mn = fmaxf(m_r[r], v);
            float alpha = __expf(m_r[r] - mn);
            m_r[r] = mn;
            float sum = 0.f;
            #pragma unroll
            for (int jt = 0; jt < 4; ++jt) { p_v[jt][r] = __expf(s_v[jt][r] - mn); sum += p_v[jt][r]; }
            #pragma unroll
            for (int off = 1; off < 16; off <<= 1) sum += __shfl_xor(sum, off);
            l_r[r] = l_r[r] * alpha + sum;
            #pragma unroll
            for (int nt = 0; nt < 8; ++nt) acc_o[nt][r] *= alpha;
        }

        // P (C-layout) -> wave-private LDS in A-layout-readable, swizzled form
        unsigned short* pw = Ps[w];
        #pragma unroll
        for (int jt = 0; jt < 4; ++jt)
            #pragma unroll
            for (int r = 0; r < 4; ++r) {
                int row = quad * 4 + r;
                int c = (2 * jt + (l16 >> 3)) ^ (row & 7);
                pw[row * 64 + c * 8 + (l16 & 7)] = f2bf(p_v[jt][r]);
            }
        // O += P V  (16 MFMAs); wave-private P needs no barrier (lgkmcnt only)
        #pragma unroll
        for (int ks = 0; ks < 2; ++ks) {
            bf16x8 ap = *(const bf16x8*)(pw + l16 * 64 + (((ks * 4 + quad) ^ (l16 & 7)) * 8));
            #pragma unroll
            for (int nt = 0; nt < 8; ++nt) {
                bf16x8 bv = *(const bf16x8*)(Vs + (nt * 16 + l16) * 64 +
                                             (((ks * 4 + quad) ^ (l16 & 7)) * 8));
                acc_o[nt] = __builtin_amdgcn_mfma_f32_16x16x32_bf16(ap, bv, acc_o[nt], 0, 0, 0);
            }
        }
    }

    #pragma unroll
    for (int r = 0; r < 4; ++r) {
        float inv = 1.f / l_r[r];
        int qrow = s0 + w * 16 + quad * 4 + r;
        unsigned short* op = ao + (size_t)qrow * (NHEAD * HDIM) + h * HDIM + l16;
        #pragma unroll
        for (int nt = 0; nt < 8; ++nt)
            op[nt * 16] = f2bf(acc_o[nt][r] * inv);
    }
}

extern "C" void kernel_launch(void* const* d_in, const int* in_sizes, int n_in,
                              void* d_out, int out_size, void* d_ws, size_t ws_size,
                              hipStream_t stream) {
    const float* hidden = (const float*)d_in[0];
    const float* cosb   = (const float*)d_in[1];
    const float* sinb   = (const float*)d_in[2];
    const float* wq     = (const float*)d_in[3];
    const float* wk     = (const float*)d_in[4];
    const float* wv     = (const float*)d_in[5];
    const float* wo     = (const float*)d_in[6];
    // d_in[7..9]: k_cache/v_cache/block_ids — scatter+gather by same ids == identity; unused.

    unsigned short* hb  = (unsigned short*)d_ws;             // hidden bf16; reused as attn out
    unsigned short* wb  = hb + (size_t)SEQ * HIDDEN;         // current weight bf16 (32 MB region)
    unsigned short* qb  = wb + (size_t)HIDDEN * HIDDEN;      // q bf16 [SEQ][4096]
    unsigned short* kb  = qb + (size_t)SEQ * NHEAD * HDIM;   // k bf16 [SEQ][1024]
    unsigned short* vtb = kb + (size_t)SEQ * NKVH * HDIM;    // v^T bf16 [1024][SEQ]
    unsigned short* ao  = hb;

    dim3 blk(256);
    cast_f32_bf16<<<dim3(SEQ * HIDDEN / 1024), blk, 0, stream>>>(hidden, hb, SEQ * HIDDEN / 4);

    // Q projection
    cast_f32_bf16<<<dim3(HIDDEN * HIDDEN / 1024), blk, 0, stream>>>(wq, wb, HIDDEN * HIDDEN / 4);
    gemm_nt_mfma<unsigned short><<<dim3((NHEAD * HDIM) / 128, SEQ / 128), blk, 0, stream>>>(
        hb, wb, qb, SEQ, NHEAD * HDIM, HIDDEN);

    // Fused K+V projection: wk -> wb rows [0,1024), wv -> wb rows [1024,2048).
    // One GEMM, N=2048, grid 16x16 = 256 WGs (full machine vs 2x 128-WG GEMMs).
    cast_f32_bf16<<<dim3(NKVH * HDIM * HIDDEN / 1024), blk, 0, stream>>>(wk, wb, NKVH * HDIM * HIDDEN / 4);
    cast_f32_bf16<<<dim3(NKVH * HDIM * HIDDEN / 1024), blk, 0, stream>>>(
        wv, wb + (size_t)(NKVH * HDIM) * HIDDEN, NKVH * HDIM * HIDDEN / 4);
    gemm_kv_mfma<<<dim3((2 * NKVH * HDIM) / 128, SEQ / 128), blk, 0, stream>>>(hb, wb, kb, vtb);

    // RoPE on q and k
    rope_bf16<<<dim3(SEQ * NHEAD * 64 / 256), blk, 0, stream>>>(qb, cosb, sinb, NHEAD);
    rope_bf16<<<dim3(SEQ * NKVH * 64 / 256), blk, 0, stream>>>(kb, cosb, sinb, NKVH);

    // MFMA flash attention
    attn_mfma<<<dim3(NQT, NHEAD), blk, 0, stream>>>(qb, kb, vtb, ao);

    // output projection (fp32 out)
    cast_f32_bf16<<<dim3(HIDDEN * HIDDEN / 1024), blk, 0, stream>>>(wo, wb, HIDDEN * HIDDEN / 4);
    gemm_nt_mfma<float><<<dim3(HIDDEN / 128, SEQ / 128), blk, 0, stream>>>(
        ao, wb, (float*)d_out, SEQ, HIDDEN, NHEAD * HDIM);
}

// Round 3
// 623.194 us; speedup vs baseline: 1.2754x; 1.2754x over previous
//
#include <hip/hip_runtime.h>
#include <hip/hip_bf16.h>
#include <stdint.h>

#define SEQ 2048
#define HIDDEN 4096
#define NHEAD 32
#define NKVH 8
#define HDIM 128
#define NQT (SEQ / 64)
#define SCALE 0.08838834764831845f

typedef __bf16 bf16x8 __attribute__((ext_vector_type(8)));
typedef float floatx4 __attribute__((ext_vector_type(4)));

__device__ inline float bf2f(unsigned int u16) {
    union { unsigned int i; float f; } x;
    x.i = u16 << 16;
    return x.f;
}
__device__ inline unsigned short f2bf(float f) {
    union { float f; unsigned int u; } x;
    x.f = f;
    unsigned int r = x.u + 0x7FFF + ((x.u >> 16) & 1);   // RNE; finite inputs
    return (unsigned short)(r >> 16);
}

// fp32 -> bf16 cast, 4 elems/thread
__global__ __launch_bounds__(256) void cast_f32_bf16(const float* __restrict__ s,
                                                     unsigned short* __restrict__ d, int n4) {
    int i = blockIdx.x * 256 + threadIdx.x;
    if (i < n4) {
        float4 v = ((const float4*)s)[i];
        ushort4 o;
        o.x = f2bf(v.x); o.y = f2bf(v.y); o.z = f2bf(v.z); o.w = f2bf(v.w);
        ((ushort4*)d)[i] = o;
    }
}

__device__ inline void storeC(float* p, float v) { *p = v; }
__device__ inline void storeC(unsigned short* p, float v) { *p = f2bf(v); }

// async 16B global->LDS; within a wave LDS dest must be base + lane*16
#define GLL16(gp, lp) __builtin_amdgcn_global_load_lds( \
    (const __attribute__((address_space(1))) unsigned int*)(gp), \
    (__attribute__((address_space(3))) unsigned int*)(lp), 16, 0, 0)

// C[m][n] = sum_k A[m][k]*B[n][k]; A: MxK bf16 row-major, B: NxK bf16 row-major.
// 128x128 tile, BK=32, 4 waves 2x2, wave does 64x64 via 4x4 of 16x16x32 MFMA.
// TRANSOUT: write C transposed as bf16 CT[n][m] (packed 4-row 8B stores).
template <typename OutT, bool TRANSOUT = false>
__global__ __launch_bounds__(256) void gemm_nt_mfma(const unsigned short* __restrict__ A,
                                                    const unsigned short* __restrict__ B,
                                                    OutT* __restrict__ C,
                                                    int M, int N, int K) {
    __shared__ unsigned short As[128 * 32];
    __shared__ unsigned short Bs[128 * 32];
    const int tid = threadIdx.x;
    const int lane = tid & 63;
    const int w = tid >> 6;
    const int m0 = blockIdx.y * 128, n0 = blockIdx.x * 128;
    const int wr = (w >> 1) * 64, wc = (w & 1) * 64;
    const int srow = tid >> 2;
    const int scol = (tid & 3) * 8;
    const int quad = lane >> 4, l16 = lane & 15;

    floatx4 acc[4][4] = {};

    for (int k0 = 0; k0 < K; k0 += 32) {
        __syncthreads();
        const unsigned short* gA = A + (size_t)(m0 + srow) * K + k0 + scol;
        const unsigned short* gB = B + (size_t)(n0 + srow) * K + k0 + scol;
        GLL16(gA,                  As + srow * 32 + scol);
        GLL16(gA + (size_t)64 * K, As + (64 + srow) * 32 + scol);
        GLL16(gB,                  Bs + srow * 32 + scol);
        GLL16(gB + (size_t)64 * K, Bs + (64 + srow) * 32 + scol);
        __syncthreads();

        bf16x8 af[4], bg[4];
        #pragma unroll
        for (int i = 0; i < 4; ++i)
            af[i] = *(const bf16x8*)(As + (wr + i * 16 + l16) * 32 + quad * 8);
        #pragma unroll
        for (int j = 0; j < 4; ++j)
            bg[j] = *(const bf16x8*)(Bs + (wc + j * 16 + l16) * 32 + quad * 8);
        #pragma unroll
        for (int i = 0; i < 4; ++i)
            #pragma unroll
            for (int j = 0; j < 4; ++j)
                acc[i][j] = __builtin_amdgcn_mfma_f32_16x16x32_bf16(af[i], bg[j], acc[i][j], 0, 0, 0);
    }

    // C/D layout: col = lane&15, row = quad*4 + reg
    #pragma unroll
    for (int i = 0; i < 4; ++i) {
        #pragma unroll
        for (int j = 0; j < 4; ++j) {
            int col = n0 + wc + j * 16 + l16;
            int rowb = m0 + wr + i * 16 + quad * 4;
            if constexpr (TRANSOUT) {
                ushort4 pk;
                pk.x = f2bf(acc[i][j][0]);
                pk.y = f2bf(acc[i][j][1]);
                pk.z = f2bf(acc[i][j][2]);
                pk.w = f2bf(acc[i][j][3]);
                *(ushort4*)&C[(size_t)col * M + rowb] = pk;
            } else {
                #pragma unroll
                for (int r = 0; r < 4; ++r)
                    storeC(&C[(size_t)(rowb + r) * N + col], acc[i][j][r]);
            }
        }
    }
}

// Fused K+V projection GEMM. A: [SEQ][HIDDEN] bf16; B: [2048][HIDDEN] bf16 where
// rows [0,1024) are wk and rows [1024,2048) are wv. Main loop identical to
// gemm_nt_mfma. Epilogue routes block-uniformly on n0:
//   n0 < 1024 -> K path: kb[row][col] bf16 (ld = 1024)
//   n0 >= 1024 -> V path: vtb[(col-1024)*SEQ + row] transposed bf16 (packed 8B)
__global__ __launch_bounds__(256) void gemm_kv_mfma(const unsigned short* __restrict__ A,
                                                    const unsigned short* __restrict__ B,
                                                    unsigned short* __restrict__ Ck,
                                                    unsigned short* __restrict__ Cvt) {
    const int M = SEQ, K = HIDDEN;
    __shared__ unsigned short As[128 * 32];
    __shared__ unsigned short Bs[128 * 32];
    const int tid = threadIdx.x;
    const int lane = tid & 63;
    const int w = tid >> 6;
    const int m0 = blockIdx.y * 128, n0 = blockIdx.x * 128;
    const int wr = (w >> 1) * 64, wc = (w & 1) * 64;
    const int srow = tid >> 2;
    const int scol = (tid & 3) * 8;
    const int quad = lane >> 4, l16 = lane & 15;

    floatx4 acc[4][4] = {};

    for (int k0 = 0; k0 < K; k0 += 32) {
        __syncthreads();
        const unsigned short* gA = A + (size_t)(m0 + srow) * K + k0 + scol;
        const unsigned short* gB = B + (size_t)(n0 + srow) * K + k0 + scol;
        GLL16(gA,                  As + srow * 32 + scol);
        GLL16(gA + (size_t)64 * K, As + (64 + srow) * 32 + scol);
        GLL16(gB,                  Bs + srow * 32 + scol);
        GLL16(gB + (size_t)64 * K, Bs + (64 + srow) * 32 + scol);
        __syncthreads();

        bf16x8 af[4], bg[4];
        #pragma unroll
        for (int i = 0; i < 4; ++i)
            af[i] = *(const bf16x8*)(As + (wr + i * 16 + l16) * 32 + quad * 8);
        #pragma unroll
        for (int j = 0; j < 4; ++j)
            bg[j] = *(const bf16x8*)(Bs + (wc + j * 16 + l16) * 32 + quad * 8);
        #pragma unroll
        for (int i = 0; i < 4; ++i)
            #pragma unroll
            for (int j = 0; j < 4; ++j)
                acc[i][j] = __builtin_amdgcn_mfma_f32_16x16x32_bf16(af[i], bg[j], acc[i][j], 0, 0, 0);
    }

    if (n0 < NKVH * HDIM) {
        const int N = NKVH * HDIM;
        #pragma unroll
        for (int i = 0; i < 4; ++i) {
            #pragma unroll
            for (int j = 0; j < 4; ++j) {
                int col = n0 + wc + j * 16 + l16;
                int rowb = m0 + wr + i * 16 + quad * 4;
                #pragma unroll
                for (int r = 0; r < 4; ++r)
                    Ck[(size_t)(rowb + r) * N + col] = f2bf(acc[i][j][r]);
            }
        }
    } else {
        #pragma unroll
        for (int i = 0; i < 4; ++i) {
            #pragma unroll
            for (int j = 0; j < 4; ++j) {
                int col = n0 - NKVH * HDIM + wc + j * 16 + l16;
                int rowb = m0 + wr + i * 16 + quad * 4;
                ushort4 pk;
                pk.x = f2bf(acc[i][j][0]);
                pk.y = f2bf(acc[i][j][1]);
                pk.z = f2bf(acc[i][j][2]);
                pk.w = f2bf(acc[i][j][3]);
                *(ushort4*)&Cvt[(size_t)col * M + rowb] = pk;
            }
        }
    }
}

// In-place RoPE on bf16 [SEQ][nh*HDIM]; cos/sin fp32, cos[s][d]==cos[s][d+64].
__global__ __launch_bounds__(256) void rope_bf16(unsigned short* __restrict__ x,
                                                 const float* __restrict__ cosb,
                                                 const float* __restrict__ sinb,
                                                 int nh) {
    int idx = blockIdx.x * 256 + threadIdx.x;
    int d = idx & 63;
    int t = idx >> 6;
    int h = t % nh;
    int s = t / nh;
    float cs = cosb[s * HDIM + d];
    float sn = sinb[s * HDIM + d];
    unsigned short* p = x + (size_t)s * nh * HDIM + h * HDIM + d;
    float x1 = bf2f(p[0]), x2 = bf2f(p[64]);
    p[0]  = f2bf(x1 * cs - x2 * sn);
    p[64] = f2bf(x2 * cs + x1 * sn);
}

// MFMA flash attention. grid (NQT/2, NHEAD), block 256 (4 waves).
// Work-balanced: block bx processes q-tile bx THEN q-tile NQT-1-bx -> every
// block does exactly NQT/2+1 + ... = 34 k-tile iterations (uniform, no tail).
// K/V staging double-buffered (minimum-2-phase pipeline): stage(t+1) issued
// before compute(t); single __syncthreads per tile drains it.
// q: bf16 [SEQ][NHEAD*HDIM] (roped); k: bf16 [SEQ][NKVH*HDIM] (roped);
// vt: bf16 [NKVH*HDIM][SEQ] (V transposed); ao: bf16 [SEQ][NHEAD*HDIM].
__global__ __launch_bounds__(256) void attn_mfma(const unsigned short* __restrict__ qg,
                                                 const unsigned short* __restrict__ kgb,
                                                 const unsigned short* __restrict__ vtg,
                                                 unsigned short* __restrict__ ao) {
    __shared__ unsigned short Ks[2][64 * 128];   // [key][dim], chunk-swizzled, dbuf
    __shared__ unsigned short Vs[2][128 * 64];   // [dim][key], chunk-swizzled, dbuf
    __shared__ unsigned short Ps[4][16 * 64];    // wave-private P, chunk-swizzled
    const int h = blockIdx.y;
    const int kvh = h >> 2;                   // NHEAD/NKVH = 4
    const int tid = threadIdx.x;
    const int w = tid >> 6, lane = tid & 63;
    const int quad = lane >> 4, l16 = lane & 15;
    const int srow16 = tid >> 4, sc16 = tid & 15;   // K staging: 16 rows x 16 chunks / call
    const int sdim8 = tid >> 3, skc8 = tid & 7;     // V staging: 32 dims x 8 chunks / call

    auto stage = [&](int buf, int t) {
        #pragma unroll
        for (int rl = 0; rl < 4; ++rl) {
            int key = rl * 16 + srow16;
            int cg = sc16 ^ (key & 7);   // swizzle on global side
            const unsigned short* gp = kgb + (size_t)(t * 64 + key) * (NKVH * HDIM) + kvh * HDIM + cg * 8;
            GLL16(gp, &Ks[buf][key * 128 + sc16 * 8]);
        }
        #pragma unroll
        for (int rl = 0; rl < 4; ++rl) {
            int dim = rl * 32 + sdim8;
            int kg2 = skc8 ^ (dim & 7);
            const unsigned short* gp = vtg + (size_t)(kvh * HDIM + dim) * SEQ + t * 64 + kg2 * 8;
            GLL16(gp, &Vs[buf][dim * 64 + skc8 * 8]);
        }
    };

    #pragma unroll 1
    for (int ph = 0; ph < 2; ++ph) {
        const int qt = ph ? (NQT - 1 - (int)blockIdx.x) : (int)blockIdx.x;
        const int s0 = qt * 64;

        // Q fragments straight from global (invariant over k-tiles)
        bf16x8 aq[4];
        {
            const unsigned short* qrowp = qg + (size_t)(s0 + w * 16 + l16) * (NHEAD * HDIM) + h * HDIM;
            #pragma unroll
            for (int ks = 0; ks < 4; ++ks)
                aq[ks] = *(const bf16x8*)(qrowp + ks * 32 + quad * 8);
        }

        floatx4 acc_o[8] = {};
        float m_r[4], l_r[4];
        #pragma unroll
        for (int r = 0; r < 4; ++r) { m_r[r] = -1e30f; l_r[r] = 0.f; }

        stage(0, 0);
        __syncthreads();          // drains vmcnt -> buf0 valid (prior phase reads already fenced)
        int cur = 0;

        for (int t = 0; t <= qt; ++t) {
            if (t < qt) stage(cur ^ 1, t + 1);   // async prefetch; drained by loop-end barrier
            const unsigned short* Kc = &Ks[cur][0];
            const unsigned short* Vc = &Vs[cur][0];

            // S = Q K^T  (16 MFMAs)
            floatx4 acc_s[4] = {};
            #pragma unroll
            for (int ks = 0; ks < 4; ++ks)
                #pragma unroll
                for (int jt = 0; jt < 4; ++jt) {
                    bf16x8 bk = *(const bf16x8*)(Kc + (jt * 16 + l16) * 128 +
                                                 (((ks * 4 + quad) ^ (l16 & 7)) * 8));
                    acc_s[jt] = __builtin_amdgcn_mfma_f32_16x16x32_bf16(aq[ks], bk, acc_s[jt], 0, 0, 0);
                }

            float s_v[4][4];
            #pragma unroll
            for (int jt = 0; jt < 4; ++jt)
                #pragma unroll
                for (int r = 0; r < 4; ++r)
                    s_v[jt][r] = acc_s[jt][r] * SCALE;
            if (t == qt) {   // diagonal tile: causal mask (block-uniform branch)
                #pragma unroll
                for (int jt = 0; jt < 4; ++jt) {
                    int key = t * 64 + jt * 16 + l16;
                    #pragma unroll
                    for (int r = 0; r < 4; ++r) {
                        int qrow = s0 + w * 16 + quad * 4 + r;
                        if (key > qrow) s_v[jt][r] = -1e30f;
                    }
                }
            }

            // online softmax; row r lives in lanes sharing quad, spread over l16
            float p_v[4][4];
            #pragma unroll
            for (int r = 0; r < 4; ++r) {
                float v = fmaxf(fmaxf(s_v[0][r], s_v[1][r]), fmaxf(s_v[2][r], s_v[3][r]));
                #pragma unroll
                for (int off = 1; off < 16; off <<= 1) v = fmaxf(v, __shfl_xor(v, off));
                float mn = fmaxf(m_r[r], v);
                float alpha = __expf(m_r[r] - mn);
                m_r[r] = mn;
                float sum = 0.f;
                #pragma unroll
                for (int jt = 0; jt < 4; ++jt) { p_v[jt][r] = __expf(s_v[jt][r] - mn); sum += p_v[jt][r]; }
                #pragma unroll
                for (int off = 1; off < 16; off <<= 1) sum += __shfl_xor(sum, off);
                l_r[r] = l_r[r] * alpha + sum;
                #pragma unroll
                for (int nt = 0; nt < 8; ++nt) acc_o[nt][r] *= alpha;
            }

            // P (C-layout) -> wave-private LDS in A-layout-readable, swizzled form
            unsigned short* pw = Ps[w];
            #pragma unroll
            for (int jt = 0; jt < 4; ++jt)
                #pragma unroll
                for (int r = 0; r < 4; ++r) {
                    int row = quad * 4 + r;
                    int c = (2 * jt + (l16 >> 3)) ^ (row & 7);
                    pw[row * 64 + c * 8 + (l16 & 7)] = f2bf(p_v[jt][r]);
                }
            // O += P V  (16 MFMAs); wave-private P needs no barrier (lgkmcnt only)
            #pragma unroll
            for (int ks = 0; ks < 2; ++ks) {
                bf16x8 ap = *(const bf16x8*)(pw + l16 * 64 + (((ks * 4 + quad) ^ (l16 & 7)) * 8));
                #pragma unroll
                for (int nt = 0; nt < 8; ++nt) {
                    bf16x8 bv = *(const bf16x8*)(Vc + (nt * 16 + l16) * 64 +
                                                 (((ks * 4 + quad) ^ (l16 & 7)) * 8));
                    acc_o[nt] = __builtin_amdgcn_mfma_f32_16x16x32_bf16(ap, bv, acc_o[nt], 0, 0, 0);
                }
            }

            __syncthreads();   // drains prefetch (next buf valid) + fences cur-buf reads
            cur ^= 1;
        }

        #pragma unroll
        for (int r = 0; r < 4; ++r) {
            float inv = 1.f / l_r[r];
            int qrow = s0 + w * 16 + quad * 4 + r;
            unsigned short* op = ao + (size_t)qrow * (NHEAD * HDIM) + h * HDIM + l16;
            #pragma unroll
            for (int nt = 0; nt < 8; ++nt)
                op[nt * 16] = f2bf(acc_o[nt][r] * inv);
        }
    }
}

extern "C" void kernel_launch(void* const* d_in, const int* in_sizes, int n_in,
                              void* d_out, int out_size, void* d_ws, size_t ws_size,
                              hipStream_t stream) {
    const float* hidden = (const float*)d_in[0];
    const float* cosb   = (const float*)d_in[1];
    const float* sinb   = (const float*)d_in[2];
    const float* wq     = (const float*)d_in[3];
    const float* wk     = (const float*)d_in[4];
    const float* wv     = (const float*)d_in[5];
    const float* wo     = (const float*)d_in[6];
    // d_in[7..9]: k_cache/v_cache/block_ids — scatter+gather by same ids == identity; unused.

    unsigned short* hb  = (unsigned short*)d_ws;             // hidden bf16; reused as attn out
    unsigned short* wb  = hb + (size_t)SEQ * HIDDEN;         // current weight bf16 (32 MB region)
    unsigned short* qb  = wb + (size_t)HIDDEN * HIDDEN;      // q bf16 [SEQ][4096]
    unsigned short* kb  = qb + (size_t)SEQ * NHEAD * HDIM;   // k bf16 [SEQ][1024]
    unsigned short* vtb = kb + (size_t)SEQ * NKVH * HDIM;    // v^T bf16 [1024][SEQ]
    unsigned short* ao  = hb;

    dim3 blk(256);
    cast_f32_bf16<<<dim3(SEQ * HIDDEN / 1024), blk, 0, stream>>>(hidden, hb, SEQ * HIDDEN / 4);

    // Q projection
    cast_f32_bf16<<<dim3(HIDDEN * HIDDEN / 1024), blk, 0, stream>>>(wq, wb, HIDDEN * HIDDEN / 4);
    gemm_nt_mfma<unsigned short><<<dim3((NHEAD * HDIM) / 128, SEQ / 128), blk, 0, stream>>>(
        hb, wb, qb, SEQ, NHEAD * HDIM, HIDDEN);

    // Fused K+V projection: wk -> wb rows [0,1024), wv -> wb rows [1024,2048).
    // One GEMM, N=2048, grid 16x16 = 256 WGs (full machine vs 2x 128-WG GEMMs).
    cast_f32_bf16<<<dim3(NKVH * HDIM * HIDDEN / 1024), blk, 0, stream>>>(wk, wb, NKVH * HDIM * HIDDEN / 4);
    cast_f32_bf16<<<dim3(NKVH * HDIM * HIDDEN / 1024), blk, 0, stream>>>(
        wv, wb + (size_t)(NKVH * HDIM) * HIDDEN, NKVH * HDIM * HIDDEN / 4);
    gemm_kv_mfma<<<dim3((2 * NKVH * HDIM) / 128, SEQ / 128), blk, 0, stream>>>(hb, wb, kb, vtb);

    // RoPE on q and k
    rope_bf16<<<dim3(SEQ * NHEAD * 64 / 256), blk, 0, stream>>>(qb, cosb, sinb, NHEAD);
    rope_bf16<<<dim3(SEQ * NKVH * 64 / 256), blk, 0, stream>>>(kb, cosb, sinb, NKVH);

    // MFMA flash attention (work-balanced qt pairing, double-buffered staging)
    attn_mfma<<<dim3(NQT / 2, NHEAD), blk, 0, stream>>>(qb, kb, vtb, ao);

    // output projection (fp32 out)
    cast_f32_bf16<<<dim3(HIDDEN * HIDDEN / 1024), blk, 0, stream>>>(wo, wb, HIDDEN * HIDDEN / 4);
    gemm_nt_mfma<float><<<dim3(HIDDEN / 128, SEQ / 128), blk, 0, stream>>>(
        ao, wb, (float*)d_out, SEQ, HIDDEN, NHEAD * HDIM);
}

// Round 4
// 552.660 us; speedup vs baseline: 1.4382x; 1.1276x over previous
//
#include <hip/hip_runtime.h>
#include <hip/hip_bf16.h>
#include <stdint.h>

#define SEQ 2048
#define HIDDEN 4096
#define NHEAD 32
#define NKVH 8
#define HDIM 128
#define NQT (SEQ / 64)
#define SCALE 0.08838834764831845f

typedef __bf16 bf16x8 __attribute__((ext_vector_type(8)));
typedef float floatx4 __attribute__((ext_vector_type(4)));

__device__ inline float bf2f(unsigned int u16) {
    union { unsigned int i; float f; } x;
    x.i = u16 << 16;
    return x.f;
}
__device__ inline unsigned short f2bf(float f) {
    union { float f; unsigned int u; } x;
    x.f = f;
    unsigned int r = x.u + 0x7FFF + ((x.u >> 16) & 1);   // RNE; finite inputs
    return (unsigned short)(r >> 16);
}

// fp32 -> bf16 cast, 4 elems/thread
__global__ __launch_bounds__(256) void cast_f32_bf16(const float* __restrict__ s,
                                                     unsigned short* __restrict__ d, int n4) {
    int i = blockIdx.x * 256 + threadIdx.x;
    if (i < n4) {
        float4 v = ((const float4*)s)[i];
        ushort4 o;
        o.x = f2bf(v.x); o.y = f2bf(v.y); o.z = f2bf(v.z); o.w = f2bf(v.w);
        ((ushort4*)d)[i] = o;
    }
}

__device__ inline void storeC(float* p, float v) { *p = v; }
__device__ inline void storeC(unsigned short* p, float v) { *p = f2bf(v); }

// async 16B global->LDS; within a wave LDS dest must be base + lane*16
#define GLL16(gp, lp) __builtin_amdgcn_global_load_lds( \
    (const __attribute__((address_space(1))) unsigned int*)(gp), \
    (__attribute__((address_space(3))) unsigned int*)(lp), 16, 0, 0)

// C[m][n] = sum_k A[m][k]*B[n][k]; A: MxK bf16 row-major, B: NxK bf16 row-major.
// 128x128 tile, BK=32, 4 waves 2x2, wave does 64x64 via 4x4 of 16x16x32 MFMA.
// Double-buffered 2-phase pipeline: stage(k+1) issued BEFORE compute(k);
// single __syncthreads per K-step drains the prefetch (validated on attn_mfma).
template <typename OutT>
__global__ __launch_bounds__(256) void gemm_nt_mfma(const unsigned short* __restrict__ A,
                                                    const unsigned short* __restrict__ B,
                                                    OutT* __restrict__ C,
                                                    int M, int N, int K) {
    __shared__ unsigned short As[2][128 * 32];
    __shared__ unsigned short Bs[2][128 * 32];
    const int tid = threadIdx.x;
    const int lane = tid & 63;
    const int w = tid >> 6;
    const int m0 = blockIdx.y * 128, n0 = blockIdx.x * 128;
    const int wr = (w >> 1) * 64, wc = (w & 1) * 64;
    const int srow = tid >> 2;
    const int scol = (tid & 3) * 8;
    const int quad = lane >> 4, l16 = lane & 15;

    auto stage = [&](int buf, int k0) {
        const unsigned short* gA = A + (size_t)(m0 + srow) * K + k0 + scol;
        const unsigned short* gB = B + (size_t)(n0 + srow) * K + k0 + scol;
        GLL16(gA,                  &As[buf][srow * 32 + scol]);
        GLL16(gA + (size_t)64 * K, &As[buf][(64 + srow) * 32 + scol]);
        GLL16(gB,                  &Bs[buf][srow * 32 + scol]);
        GLL16(gB + (size_t)64 * K, &Bs[buf][(64 + srow) * 32 + scol]);
    };

    floatx4 acc[4][4] = {};

    stage(0, 0);
    __syncthreads();          // drains vmcnt -> buf0 valid
    int cur = 0;

    for (int k0 = 0; k0 < K; k0 += 32) {
        if (k0 + 32 < K) stage(cur ^ 1, k0 + 32);   // async prefetch

        bf16x8 af[4], bg[4];
        #pragma unroll
        for (int i = 0; i < 4; ++i)
            af[i] = *(const bf16x8*)(&As[cur][(wr + i * 16 + l16) * 32 + quad * 8]);
        #pragma unroll
        for (int j = 0; j < 4; ++j)
            bg[j] = *(const bf16x8*)(&Bs[cur][(wc + j * 16 + l16) * 32 + quad * 8]);
        #pragma unroll
        for (int i = 0; i < 4; ++i)
            #pragma unroll
            for (int j = 0; j < 4; ++j)
                acc[i][j] = __builtin_amdgcn_mfma_f32_16x16x32_bf16(af[i], bg[j], acc[i][j], 0, 0, 0);

        __syncthreads();      // drains prefetch + fences cur-buf reads
        cur ^= 1;
    }

    // C/D layout: col = lane&15, row = quad*4 + reg
    #pragma unroll
    for (int i = 0; i < 4; ++i) {
        #pragma unroll
        for (int j = 0; j < 4; ++j) {
            int col = n0 + wc + j * 16 + l16;
            int rowb = m0 + wr + i * 16 + quad * 4;
            #pragma unroll
            for (int r = 0; r < 4; ++r)
                storeC(&C[(size_t)(rowb + r) * N + col], acc[i][j][r]);
        }
    }
}

// Fused Q+K+V projection GEMM. A: [SEQ][HIDDEN] bf16; B: [6144][HIDDEN] bf16
// where rows [0,4096)=wq, [4096,5120)=wk, [5120,6144)=wv. Same dbuf pipeline.
// Epilogue routes block-uniformly on n0 (tile width 128 divides all segments):
//   n0 < 4096          -> Q path: qb[row][col] bf16 (ld 4096)
//   4096 <= n0 < 5120  -> K path: kb[row][col-4096] bf16 (ld 1024)
//   n0 >= 5120         -> V path: vtb[(col-5120)*SEQ + row] transposed (8B stores)
__global__ __launch_bounds__(256) void gemm_qkv_mfma(const unsigned short* __restrict__ A,
                                                     const unsigned short* __restrict__ B,
                                                     unsigned short* __restrict__ Cq,
                                                     unsigned short* __restrict__ Ck,
                                                     unsigned short* __restrict__ Cvt) {
    const int M = SEQ, K = HIDDEN;
    __shared__ unsigned short As[2][128 * 32];
    __shared__ unsigned short Bs[2][128 * 32];
    const int tid = threadIdx.x;
    const int lane = tid & 63;
    const int w = tid >> 6;
    const int m0 = blockIdx.y * 128, n0 = blockIdx.x * 128;
    const int wr = (w >> 1) * 64, wc = (w & 1) * 64;
    const int srow = tid >> 2;
    const int scol = (tid & 3) * 8;
    const int quad = lane >> 4, l16 = lane & 15;

    auto stage = [&](int buf, int k0) {
        const unsigned short* gA = A + (size_t)(m0 + srow) * K + k0 + scol;
        const unsigned short* gB = B + (size_t)(n0 + srow) * K + k0 + scol;
        GLL16(gA,                  &As[buf][srow * 32 + scol]);
        GLL16(gA + (size_t)64 * K, &As[buf][(64 + srow) * 32 + scol]);
        GLL16(gB,                  &Bs[buf][srow * 32 + scol]);
        GLL16(gB + (size_t)64 * K, &Bs[buf][(64 + srow) * 32 + scol]);
    };

    floatx4 acc[4][4] = {};

    stage(0, 0);
    __syncthreads();
    int cur = 0;

    for (int k0 = 0; k0 < K; k0 += 32) {
        if (k0 + 32 < K) stage(cur ^ 1, k0 + 32);

        bf16x8 af[4], bg[4];
        #pragma unroll
        for (int i = 0; i < 4; ++i)
            af[i] = *(const bf16x8*)(&As[cur][(wr + i * 16 + l16) * 32 + quad * 8]);
        #pragma unroll
        for (int j = 0; j < 4; ++j)
            bg[j] = *(const bf16x8*)(&Bs[cur][(wc + j * 16 + l16) * 32 + quad * 8]);
        #pragma unroll
        for (int i = 0; i < 4; ++i)
            #pragma unroll
            for (int j = 0; j < 4; ++j)
                acc[i][j] = __builtin_amdgcn_mfma_f32_16x16x32_bf16(af[i], bg[j], acc[i][j], 0, 0, 0);

        __syncthreads();
        cur ^= 1;
    }

    if (n0 < NHEAD * HDIM) {                       // Q segment
        const int N = NHEAD * HDIM;
        #pragma unroll
        for (int i = 0; i < 4; ++i)
            #pragma unroll
            for (int j = 0; j < 4; ++j) {
                int col = n0 + wc + j * 16 + l16;
                int rowb = m0 + wr + i * 16 + quad * 4;
                #pragma unroll
                for (int r = 0; r < 4; ++r)
                    Cq[(size_t)(rowb + r) * N + col] = f2bf(acc[i][j][r]);
            }
    } else if (n0 < NHEAD * HDIM + NKVH * HDIM) {  // K segment
        const int N = NKVH * HDIM;
        #pragma unroll
        for (int i = 0; i < 4; ++i)
            #pragma unroll
            for (int j = 0; j < 4; ++j) {
                int col = n0 - NHEAD * HDIM + wc + j * 16 + l16;
                int rowb = m0 + wr + i * 16 + quad * 4;
                #pragma unroll
                for (int r = 0; r < 4; ++r)
                    Ck[(size_t)(rowb + r) * N + col] = f2bf(acc[i][j][r]);
            }
    } else {                                       // V segment (transposed out)
        #pragma unroll
        for (int i = 0; i < 4; ++i)
            #pragma unroll
            for (int j = 0; j < 4; ++j) {
                int col = n0 - (NHEAD * HDIM + NKVH * HDIM) + wc + j * 16 + l16;
                int rowb = m0 + wr + i * 16 + quad * 4;
                ushort4 pk;
                pk.x = f2bf(acc[i][j][0]);
                pk.y = f2bf(acc[i][j][1]);
                pk.z = f2bf(acc[i][j][2]);
                pk.w = f2bf(acc[i][j][3]);
                *(ushort4*)&Cvt[(size_t)col * M + rowb] = pk;
            }
    }
}

// In-place RoPE on bf16 [SEQ][nh*HDIM]; cos/sin fp32, cos[s][d]==cos[s][d+64].
__global__ __launch_bounds__(256) void rope_bf16(unsigned short* __restrict__ x,
                                                 const float* __restrict__ cosb,
                                                 const float* __restrict__ sinb,
                                                 int nh) {
    int idx = blockIdx.x * 256 + threadIdx.x;
    int d = idx & 63;
    int t = idx >> 6;
    int h = t % nh;
    int s = t / nh;
    float cs = cosb[s * HDIM + d];
    float sn = sinb[s * HDIM + d];
    unsigned short* p = x + (size_t)s * nh * HDIM + h * HDIM + d;
    float x1 = bf2f(p[0]), x2 = bf2f(p[64]);
    p[0]  = f2bf(x1 * cs - x2 * sn);
    p[64] = f2bf(x2 * cs + x1 * sn);
}

// MFMA flash attention. grid (NQT/2, NHEAD), block 256 (4 waves).
// Work-balanced: block bx processes q-tile bx THEN q-tile NQT-1-bx -> every
// block does exactly 34 k-tile iterations (uniform, no tail).
// K/V staging double-buffered (minimum-2-phase pipeline): stage(t+1) issued
// before compute(t); single __syncthreads per tile drains it.
__global__ __launch_bounds__(256) void attn_mfma(const unsigned short* __restrict__ qg,
                                                 const unsigned short* __restrict__ kgb,
                                                 const unsigned short* __restrict__ vtg,
                                                 unsigned short* __restrict__ ao) {
    __shared__ unsigned short Ks[2][64 * 128];   // [key][dim], chunk-swizzled, dbuf
    __shared__ unsigned short Vs[2][128 * 64];   // [dim][key], chunk-swizzled, dbuf
    __shared__ unsigned short Ps[4][16 * 64];    // wave-private P, chunk-swizzled
    const int h = blockIdx.y;
    const int kvh = h >> 2;                   // NHEAD/NKVH = 4
    const int tid = threadIdx.x;
    const int w = tid >> 6, lane = tid & 63;
    const int quad = lane >> 4, l16 = lane & 15;
    const int srow16 = tid >> 4, sc16 = tid & 15;   // K staging: 16 rows x 16 chunks / call
    const int sdim8 = tid >> 3, skc8 = tid & 7;     // V staging: 32 dims x 8 chunks / call

    auto stage = [&](int buf, int t) {
        #pragma unroll
        for (int rl = 0; rl < 4; ++rl) {
            int key = rl * 16 + srow16;
            int cg = sc16 ^ (key & 7);   // swizzle on global side
            const unsigned short* gp = kgb + (size_t)(t * 64 + key) * (NKVH * HDIM) + kvh * HDIM + cg * 8;
            GLL16(gp, &Ks[buf][key * 128 + sc16 * 8]);
        }
        #pragma unroll
        for (int rl = 0; rl < 4; ++rl) {
            int dim = rl * 32 + sdim8;
            int kg2 = skc8 ^ (dim & 7);
            const unsigned short* gp = vtg + (size_t)(kvh * HDIM + dim) * SEQ + t * 64 + kg2 * 8;
            GLL16(gp, &Vs[buf][dim * 64 + skc8 * 8]);
        }
    };

    #pragma unroll 1
    for (int ph = 0; ph < 2; ++ph) {
        const int qt = ph ? (NQT - 1 - (int)blockIdx.x) : (int)blockIdx.x;
        const int s0 = qt * 64;

        // Q fragments straight from global (invariant over k-tiles)
        bf16x8 aq[4];
        {
            const unsigned short* qrowp = qg + (size_t)(s0 + w * 16 + l16) * (NHEAD * HDIM) + h * HDIM;
            #pragma unroll
            for (int ks = 0; ks < 4; ++ks)
                aq[ks] = *(const bf16x8*)(qrowp + ks * 32 + quad * 8);
        }

        floatx4 acc_o[8] = {};
        float m_r[4], l_r[4];
        #pragma unroll
        for (int r = 0; r < 4; ++r) { m_r[r] = -1e30f; l_r[r] = 0.f; }

        stage(0, 0);
        __syncthreads();          // drains vmcnt -> buf0 valid
        int cur = 0;

        for (int t = 0; t <= qt; ++t) {
            if (t < qt) stage(cur ^ 1, t + 1);   // async prefetch; drained by loop-end barrier
            const unsigned short* Kc = &Ks[cur][0];
            const unsigned short* Vc = &Vs[cur][0];

            // S = Q K^T  (16 MFMAs)
            floatx4 acc_s[4] = {};
            #pragma unroll
            for (int ks = 0; ks < 4; ++ks)
                #pragma unroll
                for (int jt = 0; jt < 4; ++jt) {
                    bf16x8 bk = *(const bf16x8*)(Kc + (jt * 16 + l16) * 128 +
                                                 (((ks * 4 + quad) ^ (l16 & 7)) * 8));
                    acc_s[jt] = __builtin_amdgcn_mfma_f32_16x16x32_bf16(aq[ks], bk, acc_s[jt], 0, 0, 0);
                }

            float s_v[4][4];
            #pragma unroll
            for (int jt = 0; jt < 4; ++jt)
                #pragma unroll
                for (int r = 0; r < 4; ++r)
                    s_v[jt][r] = acc_s[jt][r] * SCALE;
            if (t == qt) {   // diagonal tile: causal mask (block-uniform branch)
                #pragma unroll
                for (int jt = 0; jt < 4; ++jt) {
                    int key = t * 64 + jt * 16 + l16;
                    #pragma unroll
                    for (int r = 0; r < 4; ++r) {
                        int qrow = s0 + w * 16 + quad * 4 + r;
                        if (key > qrow) s_v[jt][r] = -1e30f;
                    }
                }
            }

            // online softmax; row r lives in lanes sharing quad, spread over l16
            float p_v[4][4];
            #pragma unroll
            for (int r = 0; r < 4; ++r) {
                float v = fmaxf(fmaxf(s_v[0][r], s_v[1][r]), fmaxf(s_v[2][r], s_v[3][r]));
                #pragma unroll
                for (int off = 1; off < 16; off <<= 1) v = fmaxf(v, __shfl_xor(v, off));
                float mn = fmaxf(m_r[r], v);
                float alpha = __expf(m_r[r] - mn);
                m_r[r] = mn;
                float sum = 0.f;
                #pragma unroll
                for (int jt = 0; jt < 4; ++jt) { p_v[jt][r] = __expf(s_v[jt][r] - mn); sum += p_v[jt][r]; }
                #pragma unroll
                for (int off = 1; off < 16; off <<= 1) sum += __shfl_xor(sum, off);
                l_r[r] = l_r[r] * alpha + sum;
                #pragma unroll
                for (int nt = 0; nt < 8; ++nt) acc_o[nt][r] *= alpha;
            }

            // P (C-layout) -> wave-private LDS in A-layout-readable, swizzled form
            unsigned short* pw = Ps[w];
            #pragma unroll
            for (int jt = 0; jt < 4; ++jt)
                #pragma unroll
                for (int r = 0; r < 4; ++r) {
                    int row = quad * 4 + r;
                    int c = (2 * jt + (l16 >> 3)) ^ (row & 7);
                    pw[row * 64 + c * 8 + (l16 & 7)] = f2bf(p_v[jt][r]);
                }
            // O += P V  (16 MFMAs); wave-private P needs no barrier (lgkmcnt only)
            #pragma unroll
            for (int ks = 0; ks < 2; ++ks) {
                bf16x8 ap = *(const bf16x8*)(pw + l16 * 64 + (((ks * 4 + quad) ^ (l16 & 7)) * 8));
                #pragma unroll
                for (int nt = 0; nt < 8; ++nt) {
                    bf16x8 bv = *(const bf16x8*)(Vc + (nt * 16 + l16) * 64 +
                                                 (((ks * 4 + quad) ^ (l16 & 7)) * 8));
                    acc_o[nt] = __builtin_amdgcn_mfma_f32_16x16x32_bf16(ap, bv, acc_o[nt], 0, 0, 0);
                }
            }

            __syncthreads();   // drains prefetch (next buf valid) + fences cur-buf reads
            cur ^= 1;
        }

        #pragma unroll
        for (int r = 0; r < 4; ++r) {
            float inv = 1.f / l_r[r];
            int qrow = s0 + w * 16 + quad * 4 + r;
            unsigned short* op = ao + (size_t)qrow * (NHEAD * HDIM) + h * HDIM + l16;
            #pragma unroll
            for (int nt = 0; nt < 8; ++nt)
                op[nt * 16] = f2bf(acc_o[nt][r] * inv);
        }
    }
}

extern "C" void kernel_launch(void* const* d_in, const int* in_sizes, int n_in,
                              void* d_out, int out_size, void* d_ws, size_t ws_size,
                              hipStream_t stream) {
    const float* hidden = (const float*)d_in[0];
    const float* cosb   = (const float*)d_in[1];
    const float* sinb   = (const float*)d_in[2];
    const float* wq     = (const float*)d_in[3];
    const float* wk     = (const float*)d_in[4];
    const float* wv     = (const float*)d_in[5];
    const float* wo     = (const float*)d_in[6];
    // d_in[7..9]: k_cache/v_cache/block_ids — scatter+gather by same ids == identity; unused.

    unsigned short* hb   = (unsigned short*)d_ws;                  // hidden bf16; reused as attn out
    unsigned short* wqkv = hb + (size_t)SEQ * HIDDEN;              // [6144][4096] bf16 (wq;wk;wv); reused for wo
    unsigned short* qb   = wqkv + (size_t)(NHEAD + 2 * NKVH) * HDIM * HIDDEN;  // q bf16 [SEQ][4096]
    unsigned short* kb   = qb + (size_t)SEQ * NHEAD * HDIM;        // k bf16 [SEQ][1024]
    unsigned short* vtb  = kb + (size_t)SEQ * NKVH * HDIM;         // v^T bf16 [1024][SEQ]
    unsigned short* ao   = hb;

    dim3 blk(256);
    cast_f32_bf16<<<dim3(SEQ * HIDDEN / 1024), blk, 0, stream>>>(hidden, hb, SEQ * HIDDEN / 4);

    // Cast wq/wk/wv into one stacked weight buffer: rows [0,4096)=wq, [4096,5120)=wk, [5120,6144)=wv
    cast_f32_bf16<<<dim3(HIDDEN * HIDDEN / 1024), blk, 0, stream>>>(wq, wqkv, HIDDEN * HIDDEN / 4);
    cast_f32_bf16<<<dim3(NKVH * HDIM * HIDDEN / 1024), blk, 0, stream>>>(
        wk, wqkv + (size_t)NHEAD * HDIM * HIDDEN, NKVH * HDIM * HIDDEN / 4);
    cast_f32_bf16<<<dim3(NKVH * HDIM * HIDDEN / 1024), blk, 0, stream>>>(
        wv, wqkv + (size_t)(NHEAD + NKVH) * HDIM * HIDDEN, NKVH * HDIM * HIDDEN / 4);

    // Fused QKV projection: N=6144, grid 48x16 = 768 WGs (3 blocks/CU)
    gemm_qkv_mfma<<<dim3((NHEAD + 2 * NKVH) * HDIM / 128, SEQ / 128), blk, 0, stream>>>(
        hb, wqkv, qb, kb, vtb);

    // RoPE on q and k
    rope_bf16<<<dim3(SEQ * NHEAD * 64 / 256), blk, 0, stream>>>(qb, cosb, sinb, NHEAD);
    rope_bf16<<<dim3(SEQ * NKVH * 64 / 256), blk, 0, stream>>>(kb, cosb, sinb, NKVH);

    // MFMA flash attention (work-balanced qt pairing, double-buffered staging)
    attn_mfma<<<dim3(NQT / 2, NHEAD), blk, 0, stream>>>(qb, kb, vtb, ao);

    // output projection (fp32 out)
    cast_f32_bf16<<<dim3(HIDDEN * HIDDEN / 1024), blk, 0, stream>>>(wo, wqkv, HIDDEN * HIDDEN / 4);
    gemm_nt_mfma<float><<<dim3(HIDDEN / 128, SEQ / 128), blk, 0, stream>>>(
        ao, wqkv, (float*)d_out, SEQ, HIDDEN, NHEAD * HDIM);
}